// Round 1
// baseline (256.417 us; speedup 1.0000x reference)
//
#include <hip/hip_runtime.h>

#define BATCH 4096
#define D 128

// ws layout (as int*):
// [0 .. 4096]          starts (4097 entries): starts[b] = first atom index of graph b
// [4100]               max_atoms
// [4101]               keep_count
// [4102]               int64_flag (1 if molecule_indicator is int64 in memory)
// [4104 .. 4104+4096)  kept_to_orig mapping

__global__ void detect_dtype_kernel(const int* __restrict__ mi, int total, int* __restrict__ ws) {
    // Sorted int32 indicator ends near BATCH-1 (>0 w.p. ~1).
    // Little-endian int64: mi32[total-1] is a high word == 0.
    if (threadIdx.x == 0 && blockIdx.x == 0) {
        ws[4102] = (mi[total - 1] == 0) ? 1 : 0;
    }
}

__global__ void compute_starts_kernel(const int* __restrict__ mi, int total, int* __restrict__ ws) {
    int t = blockIdx.x * blockDim.x + threadIdx.x;
    if (t > BATCH) return;
    const int is64 = ws[4102];
    // lower_bound: first index i with mi[i] >= t  (count of elements < t)
    int lo = 0, hi = total;
    while (lo < hi) {
        int mid = (lo + hi) >> 1;
        int v = is64 ? mi[(long long)mid << 1] : mi[mid];
        if (v < t) lo = mid + 1; else hi = mid;
    }
    ws[t] = lo;
}

__global__ __launch_bounds__(1024) void compute_meta_kernel(int* __restrict__ ws) {
    // single block, 1024 threads; each thread owns 4 consecutive graphs
    const int* starts = ws;
    int* kept = ws + 4104;
    __shared__ int smax[1024];
    __shared__ int ssum[1024];
    const int tid = threadIdx.x;

    int cnt4[4];
    int localmax = 0;
    int localkeep = 0;
#pragma unroll
    for (int j = 0; j < 4; ++j) {
        int b = tid * 4 + j;
        int c = starts[b + 1] - starts[b];
        cnt4[j] = c;
        localmax = max(localmax, c);
        localkeep += (c > 0) ? 1 : 0;
    }
    smax[tid] = localmax;
    ssum[tid] = localkeep;
    __syncthreads();

    // max-reduce over 1024
    for (int s = 512; s > 0; s >>= 1) {
        if (tid < s) smax[tid] = max(smax[tid], smax[tid + s]);
        __syncthreads();
    }
    // Hillis-Steele inclusive scan of keep counts over 1024 thread-partials
    for (int off = 1; off < 1024; off <<= 1) {
        int v = (tid >= off) ? ssum[tid - off] : 0;
        __syncthreads();
        ssum[tid] += v;
        __syncthreads();
    }
    int excl = ssum[tid] - localkeep;  // exclusive prefix for this thread's group
    int o = excl;
#pragma unroll
    for (int j = 0; j < 4; ++j) {
        int b = tid * 4 + j;
        if (cnt4[j] > 0) kept[o++] = b;
    }
    if (tid == 0)    ws[4100] = smax[0];
    if (tid == 1023) ws[4101] = ssum[1023];
}

__global__ __launch_bounds__(256) void fill_out_kernel(const float4* __restrict__ in4,
                                                       const int* __restrict__ ws,
                                                       float4* __restrict__ out4,
                                                       int n4) {
    const int* starts = ws;
    const int* kept = ws + 4104;
    const int max_atoms = ws[4100];

    int idx = blockIdx.x * blockDim.x + threadIdx.x;
    const int stride = gridDim.x * blockDim.x;
    for (; idx < n4; idx += stride) {
        int r = idx >> 5;          // output row (32 float4 per row of D=128)
        int c = idx & 31;          // float4 column within row
        int g = r / max_atoms;     // kept-graph index
        int row = r - g * max_atoms;
        int b = kept[g];
        int s = starts[b];
        int cnt = starts[b + 1] - s;
        float4 v = make_float4(0.f, 0.f, 0.f, 0.f);
        if (row < cnt) {
            v = in4[((s + row) << 5) + c];
        }
        out4[idx] = v;
    }
}

extern "C" void kernel_launch(void* const* d_in, const int* in_sizes, int n_in,
                              void* d_out, int out_size, void* d_ws, size_t ws_size,
                              hipStream_t stream) {
    const float* feat = (const float*)d_in[0];
    const int* mi = (const int*)d_in[1];
    const int total = in_sizes[1];   // TOTAL atoms
    float* out = (float*)d_out;
    int* ws = (int*)d_ws;

    detect_dtype_kernel<<<1, 64, 0, stream>>>(mi, total, ws);
    compute_starts_kernel<<<(BATCH + 1 + 255) / 256, 256, 0, stream>>>(mi, total, ws);
    compute_meta_kernel<<<1, 1024, 0, stream>>>(ws);

    const int n4 = out_size / 4;
    fill_out_kernel<<<2048, 256, 0, stream>>>((const float4*)feat, ws, (float4*)out, n4);
}

// Round 3
// 250.623 us; speedup vs baseline: 1.0231x; 1.0231x over previous
//
#include <hip/hip_runtime.h>

#define BATCH 4096
#define D 128

typedef float floatx4 __attribute__((ext_vector_type(4)));

// ws layout (as int*):
// [0 .. 4096]          starts (4097 entries): starts[b] = first atom index of graph b
// [4100]               max_atoms
// [4101]               keep_count
// [4102]               int64_flag (1 if molecule_indicator is int64 in memory)
// [4104 .. 4104+4096)  kept_to_orig mapping

__global__ void detect_dtype_kernel(const int* __restrict__ mi, int total, int* __restrict__ ws) {
    // Sorted int32 indicator ends near BATCH-1 (>0 w.p. ~1).
    // Little-endian int64: mi32[total-1] is a high word == 0.
    if (threadIdx.x == 0 && blockIdx.x == 0) {
        ws[4102] = (mi[total - 1] == 0) ? 1 : 0;
    }
}

__global__ void compute_starts_kernel(const int* __restrict__ mi, int total, int* __restrict__ ws) {
    int t = blockIdx.x * blockDim.x + threadIdx.x;
    if (t > BATCH) return;
    const int is64 = ws[4102];
    // lower_bound: first index i with mi[i] >= t  (count of elements < t)
    int lo = 0, hi = total;
    while (lo < hi) {
        int mid = (lo + hi) >> 1;
        int v = is64 ? mi[(long long)mid << 1] : mi[mid];
        if (v < t) lo = mid + 1; else hi = mid;
    }
    ws[t] = lo;
}

__global__ __launch_bounds__(1024) void compute_meta_kernel(int* __restrict__ ws) {
    // single block, 1024 threads; each thread owns 4 consecutive graphs
    const int* starts = ws;
    int* kept = ws + 4104;
    __shared__ int smax[1024];
    __shared__ int ssum[1024];
    const int tid = threadIdx.x;

    int cnt4[4];
    int localmax = 0;
    int localkeep = 0;
#pragma unroll
    for (int j = 0; j < 4; ++j) {
        int b = tid * 4 + j;
        int c = starts[b + 1] - starts[b];
        cnt4[j] = c;
        localmax = max(localmax, c);
        localkeep += (c > 0) ? 1 : 0;
    }
    smax[tid] = localmax;
    ssum[tid] = localkeep;
    __syncthreads();

    // max-reduce over 1024
    for (int s = 512; s > 0; s >>= 1) {
        if (tid < s) smax[tid] = max(smax[tid], smax[tid + s]);
        __syncthreads();
    }
    // Hillis-Steele inclusive scan of keep counts over 1024 thread-partials
    for (int off = 1; off < 1024; off <<= 1) {
        int v = (tid >= off) ? ssum[tid - off] : 0;
        __syncthreads();
        ssum[tid] += v;
        __syncthreads();
    }
    int excl = ssum[tid] - localkeep;  // exclusive prefix for this thread's group
    int o = excl;
#pragma unroll
    for (int j = 0; j < 4; ++j) {
        int b = tid * 4 + j;
        if (cnt4[j] > 0) kept[o++] = b;
    }
    if (tid == 0)    ws[4100] = smax[0];
    if (tid == 1023) ws[4101] = ssum[1023];
}

__global__ __launch_bounds__(256) void fill_out_kernel(const floatx4* __restrict__ in4,
                                                       const int* __restrict__ ws,
                                                       floatx4* __restrict__ out4,
                                                       int n4) {
    const int* starts = ws;
    const int* kept = ws + 4104;
    const int max_atoms = ws[4100];

    int idx = blockIdx.x * blockDim.x + threadIdx.x;
    const int stride = gridDim.x * blockDim.x;
    for (; idx < n4; idx += stride) {
        int r = idx >> 5;          // output row (32 float4 per row of D=128)
        int c = idx & 31;          // float4 column within row
        int g = r / max_atoms;     // kept-graph index
        int row = r - g * max_atoms;
        int b = kept[g];
        int s = starts[b];
        int cnt = starts[b + 1] - s;
        floatx4 v = (floatx4)(0.f);
        if (row < cnt) {
            v = in4[((s + row) << 5) + c];
        }
        // streaming store: don't let the 671 MB output stream evict the
        // feature working set from L2/L3
        __builtin_nontemporal_store(v, &out4[idx]);
    }
}

extern "C" void kernel_launch(void* const* d_in, const int* in_sizes, int n_in,
                              void* d_out, int out_size, void* d_ws, size_t ws_size,
                              hipStream_t stream) {
    const float* feat = (const float*)d_in[0];
    const int* mi = (const int*)d_in[1];
    const int total = in_sizes[1];   // TOTAL atoms
    float* out = (float*)d_out;
    int* ws = (int*)d_ws;

    detect_dtype_kernel<<<1, 64, 0, stream>>>(mi, total, ws);
    compute_starts_kernel<<<(BATCH + 1 + 255) / 256, 256, 0, stream>>>(mi, total, ws);
    compute_meta_kernel<<<1, 1024, 0, stream>>>(ws);

    const int n4 = out_size / 4;
    fill_out_kernel<<<4096, 256, 0, stream>>>((const floatx4*)feat, ws, (floatx4*)out, n4);
}

// Round 4
// 223.232 us; speedup vs baseline: 1.1487x; 1.1227x over previous
//
#include <hip/hip_runtime.h>

#define BATCH 4096
#define D 128
#define SPLIT 4   // blocks per graph

typedef float floatx4 __attribute__((ext_vector_type(4)));

// ws layout (as int*):
// [0 .. 4096]          starts (4097 entries): starts[b] = first atom index of graph b
// [4100]               max_atoms
// [4101]               keep_count
// [4102]               int64_flag (1 if molecule_indicator is int64 in memory)
// [4104 .. 4104+4096)  kept_to_orig mapping

__global__ void detect_dtype_kernel(const int* __restrict__ mi, int total, int* __restrict__ ws) {
    // Sorted int32 indicator ends near BATCH-1 (>0 w.p. ~1).
    // Little-endian int64: mi32[total-1] is a high word == 0.
    if (threadIdx.x == 0 && blockIdx.x == 0) {
        ws[4102] = (mi[total - 1] == 0) ? 1 : 0;
    }
}

__global__ void compute_starts_kernel(const int* __restrict__ mi, int total, int* __restrict__ ws) {
    int t = blockIdx.x * blockDim.x + threadIdx.x;
    if (t > BATCH) return;
    const int is64 = ws[4102];
    // lower_bound: first index i with mi[i] >= t  (count of elements < t)
    int lo = 0, hi = total;
    while (lo < hi) {
        int mid = (lo + hi) >> 1;
        int v = is64 ? mi[(long long)mid << 1] : mi[mid];
        if (v < t) lo = mid + 1; else hi = mid;
    }
    ws[t] = lo;
}

__global__ __launch_bounds__(1024) void compute_meta_kernel(int* __restrict__ ws) {
    // single block, 1024 threads; each thread owns 4 consecutive graphs
    const int* starts = ws;
    int* kept = ws + 4104;
    __shared__ int smax[1024];
    __shared__ int ssum[1024];
    const int tid = threadIdx.x;

    int cnt4[4];
    int localmax = 0;
    int localkeep = 0;
#pragma unroll
    for (int j = 0; j < 4; ++j) {
        int b = tid * 4 + j;
        int c = starts[b + 1] - starts[b];
        cnt4[j] = c;
        localmax = max(localmax, c);
        localkeep += (c > 0) ? 1 : 0;
    }
    smax[tid] = localmax;
    ssum[tid] = localkeep;
    __syncthreads();

    // max-reduce over 1024
    for (int s = 512; s > 0; s >>= 1) {
        if (tid < s) smax[tid] = max(smax[tid], smax[tid + s]);
        __syncthreads();
    }
    // Hillis-Steele inclusive scan of keep counts over 1024 thread-partials
    for (int off = 1; off < 1024; off <<= 1) {
        int v = (tid >= off) ? ssum[tid - off] : 0;
        __syncthreads();
        ssum[tid] += v;
        __syncthreads();
    }
    int excl = ssum[tid] - localkeep;  // exclusive prefix for this thread's group
    int o = excl;
#pragma unroll
    for (int j = 0; j < 4; ++j) {
        int b = tid * 4 + j;
        if (cnt4[j] > 0) kept[o++] = b;
    }
    if (tid == 0)    ws[4100] = smax[0];
    if (tid == 1023) ws[4101] = ssum[1023];
}

// One block per (kept-graph, quarter). Graph b's output block is a contiguous
// memcpy of input rows [s, s+cnt) followed by a contiguous zero-fill — no
// per-iteration metadata loads, no divides: pure streaming copy.
__global__ __launch_bounds__(256) void copy_graph_kernel(const floatx4* __restrict__ in4,
                                                         const int* __restrict__ ws,
                                                         floatx4* __restrict__ out4) {
    const int g = blockIdx.x / SPLIT;       // kept-graph index
    const int p = blockIdx.x - g * SPLIT;   // quarter
    const int keep_count = ws[4101];
    if (g >= keep_count) return;

    const int b = ws[4104 + g];
    const int s = ws[b];
    const int cnt = ws[b + 1] - s;
    const int max_atoms = ws[4100];

    const floatx4* __restrict__ src = in4 + (s << 5);          // 32 float4 per row
    floatx4* __restrict__ dst = out4 + (g * max_atoms << 5);
    const int ncopy = cnt << 5;
    const int ntot = max_atoms << 5;

    int i = threadIdx.x + (p << 8);         // start offset for this quarter
    const int stride = 256 * SPLIT;

    // copy region: independent iterations, clean MLP
#pragma unroll 4
    for (; i < ncopy; i += stride) {
        __builtin_nontemporal_store(__builtin_nontemporal_load(&src[i]), &dst[i]);
    }
    // zero-fill region: each thread continues from where it stopped, so the
    // two loops together cover [0, ntot) exactly once
#pragma unroll 4
    for (; i < ntot; i += stride) {
        __builtin_nontemporal_store((floatx4)(0.f), &dst[i]);
    }
}

extern "C" void kernel_launch(void* const* d_in, const int* in_sizes, int n_in,
                              void* d_out, int out_size, void* d_ws, size_t ws_size,
                              hipStream_t stream) {
    const float* feat = (const float*)d_in[0];
    const int* mi = (const int*)d_in[1];
    const int total = in_sizes[1];   // TOTAL atoms
    float* out = (float*)d_out;
    int* ws = (int*)d_ws;

    detect_dtype_kernel<<<1, 64, 0, stream>>>(mi, total, ws);
    compute_starts_kernel<<<(BATCH + 1 + 255) / 256, 256, 0, stream>>>(mi, total, ws);
    compute_meta_kernel<<<1, 1024, 0, stream>>>(ws);

    copy_graph_kernel<<<BATCH * SPLIT, 256, 0, stream>>>((const floatx4*)feat, ws, (floatx4*)out);
}